// Round 1
// baseline (486.820 us; speedup 1.0000x reference)
//
#include <hip/hip_runtime.h>
#include <math.h>

#define LNUM 3
#define ENUM 8
#define TOPK 2
#define BSZ 256
#define NSZ 1024
#define DSZ 512
#define SSZ 128   // DS

// ---------------- layer kernel ----------------
// grid = BSZ blocks, block = 256 threads. Block b handles token b.
__global__ __launch_bounds__(256) void layer_kernel(
    const float* __restrict__ h_in,    // [B][D]
    float* __restrict__ h_out,         // [B][D] (may alias h_in; row-local)
    const float* __restrict__ Wg,      // [D][E]   (layer slice)
    const float* __restrict__ bg,      // [E]
    const float* __restrict__ A,       // [E][DS]
    const float* __restrict__ Bin,     // [E][D][DS]
    const float* __restrict__ Cout,    // [E][DS][D]
    const float* __restrict__ Dsk,     // [E][D]
    const float* __restrict__ states,  // [E][B][DS] (layer slice)
    float* __restrict__ out_states,    // [E][B][DS]
    float* __restrict__ acc_probs,     // [E]
    float* __restrict__ acc_sel)       // [E]
{
    const int b = blockIdx.x;
    const int t = threadIdx.x;
    const int wave = t >> 6;
    const int lane = t & 63;

    __shared__ float h_s[DSZ];
    __shared__ float logit_s[ENUM];
    __shared__ float snew_s[TOPK][SSZ];

    // load h row
    for (int i = t; i < DSZ; i += 256) h_s[i] = h_in[b * DSZ + i];
    __syncthreads();

    // gating logits: wave w computes experts 2w, 2w+1
    for (int j = 0; j < 2; ++j) {
        const int e = wave * 2 + j;
        float p = 0.f;
        for (int d = lane; d < DSZ; d += 64) p = fmaf(h_s[d], Wg[d * ENUM + e], p);
        for (int off = 32; off; off >>= 1) p += __shfl_down(p, off, 64);
        if (lane == 0) logit_s[e] = p + bg[e];
    }
    __syncthreads();

    // every thread computes softmax + top2 redundantly (identical results)
    float probs[ENUM];
    float mx = logit_s[0];
    for (int e = 1; e < ENUM; ++e) mx = fmaxf(mx, logit_s[e]);
    float ssum = 0.f;
    for (int e = 0; e < ENUM; ++e) { probs[e] = expf(logit_s[e] - mx); ssum += probs[e]; }
    const float sinv = 1.f / ssum;
    for (int e = 0; e < ENUM; ++e) probs[e] *= sinv;

    int i0 = 0;
    for (int e = 1; e < ENUM; ++e) if (probs[e] > probs[i0]) i0 = e;
    int i1 = -1;
    for (int e = 0; e < ENUM; ++e) {
        if (e == i0) continue;
        if (i1 < 0 || probs[e] > probs[i1]) i1 = e;
    }
    float g0 = probs[i0], g1 = probs[i1];
    const float ginv = 1.f / (g0 + g1);
    g0 *= ginv; g1 *= ginv;

    if (t < ENUM) {
        atomicAdd(&acc_probs[t], probs[t]);
        atomicAdd(&acc_sel[t], (t == i0 || t == i1) ? 1.0f : 0.0f);
    }

    // s_new for the two selected experts: k = t>>7 picks expert, s = t&127
    {
        const int k = t >> 7;
        const int s = t & (SSZ - 1);
        const int e = k ? i1 : i0;
        const float* Bp = Bin + (size_t)e * DSZ * SSZ + s;
        float acc = 0.f;
        #pragma unroll 4
        for (int d = 0; d < DSZ; ++d) acc = fmaf(h_s[d], Bp[d * SSZ], acc);
        const float a = A[e * SSZ + s];
        const float decay = 1.f / (1.f + expf(-a));
        const float sv = states[((size_t)e * BSZ + b) * SSZ + s];
        snew_s[k][s] = decay * sv + acc;
    }
    __syncthreads();

    // write new_states for all experts (selected: s_new, else passthrough)
    for (int idx = t; idx < ENUM * SSZ; idx += 256) {
        const int e = idx >> 7;
        const int s = idx & (SSZ - 1);
        float v;
        if (e == i0)      v = snew_s[0][s];
        else if (e == i1) v = snew_s[1][s];
        else              v = states[((size_t)e * BSZ + b) * SSZ + s];
        out_states[((size_t)e * BSZ + b) * SSZ + s] = v;
    }

    // y = s_new @ Cout + h*Dsk ; out = g0*y0 + g1*y1 ; h_out = h + out
    for (int d = t; d < DSZ; d += 256) {
        const float* C0 = Cout + (size_t)i0 * SSZ * DSZ + d;
        const float* C1 = Cout + (size_t)i1 * SSZ * DSZ + d;
        float acc0 = 0.f, acc1 = 0.f;
        #pragma unroll 4
        for (int s = 0; s < SSZ; ++s) {
            acc0 = fmaf(snew_s[0][s], C0[s * DSZ], acc0);
            acc1 = fmaf(snew_s[1][s], C1[s * DSZ], acc1);
        }
        const float hd = h_s[d];
        const float y0 = acc0 + hd * Dsk[i0 * DSZ + d];
        const float y1 = acc1 + hd * Dsk[i1 * DSZ + d];
        h_out[b * DSZ + d] = hd + g0 * y0 + g1 * y1;
    }
}

// ---------------- q = h @ Wq + bq ----------------
__global__ __launch_bounds__(256) void q_kernel(
    const float* __restrict__ h, const float* __restrict__ Wq,
    const float* __restrict__ bq, float* __restrict__ q)
{
    const int b = blockIdx.x;
    const int t = threadIdx.x;
    __shared__ float h_s[DSZ];
    for (int i = t; i < DSZ; i += 256) h_s[i] = h[b * DSZ + i];
    __syncthreads();
    for (int d = t; d < DSZ; d += 256) {
        float acc = bq[d];
        const float* W = Wq + d;
        #pragma unroll 4
        for (int dd = 0; dd < DSZ; ++dd) acc = fmaf(h_s[dd], W[dd * DSZ], acc);
        q[b * DSZ + d] = acc;
    }
}

// ---------------- logits[b,n] = q[b] . node_emb[b,n,:] / sqrt(D) ----------------
// grid = (8, B), block = 256 (4 waves). Each wave: 32 n's, one row-dot each.
__global__ __launch_bounds__(256) void logits_kernel(
    const float* __restrict__ q, const float* __restrict__ node_emb,
    float* __restrict__ logits)
{
    const int b = blockIdx.y;
    const int wave = threadIdx.x >> 6;
    const int lane = threadIdx.x & 63;

    const float4* q4 = (const float4*)(q + b * DSZ);
    const float4 q0 = q4[lane];
    const float4 q1 = q4[lane + 64];
    const float scale = 0.04419417382415922f;  // 1/sqrt(512)

    const int n0 = blockIdx.x * 128 + wave * 32;
    for (int i = 0; i < 32; ++i) {
        const int n = n0 + i;
        const float4* r = (const float4*)(node_emb + ((size_t)b * NSZ + n) * DSZ);
        const float4 a0 = r[lane];
        const float4 a1 = r[lane + 64];
        float dot = a0.x * q0.x + a0.y * q0.y + a0.z * q0.z + a0.w * q0.w
                  + a1.x * q1.x + a1.y * q1.y + a1.z * q1.z + a1.w * q1.w;
        for (int off = 32; off; off >>= 1) dot += __shfl_down(dot, off, 64);
        if (lane == 0) logits[b * NSZ + n] = dot * scale;
    }
}

// ---------------- lb_loss finisher ----------------
__global__ void loss_kernel(const float* __restrict__ acc, float* __restrict__ out)
{
    if (threadIdx.x == 0 && blockIdx.x == 0) {
        float lb = 0.f;
        for (int l = 0; l < LNUM; ++l) {
            for (int e = 0; e < ENUM; ++e) {
                const float mp = acc[(l * 2 + 0) * ENUM + e] * (1.0f / BSZ);
                const float ms = acc[(l * 2 + 1) * ENUM + e] * (1.0f / BSZ);
                lb += (float)ENUM * mp * ms;
            }
        }
        out[0] = lb;
    }
}

extern "C" void kernel_launch(void* const* d_in, const int* in_sizes, int n_in,
                              void* d_out, int out_size, void* d_ws, size_t ws_size,
                              hipStream_t stream) {
    const float* token    = (const float*)d_in[0];  // B,1,D
    const float* node_emb = (const float*)d_in[1];  // B,N,D
    const float* states   = (const float*)d_in[2];  // L,E,B,DS
    const float* Wg       = (const float*)d_in[3];  // L,D,E
    const float* bg       = (const float*)d_in[4];  // L,E
    const float* A        = (const float*)d_in[5];  // L,E,DS
    const float* Bin      = (const float*)d_in[6];  // L,E,D,DS
    const float* Cout     = (const float*)d_in[7];  // L,E,DS,D
    const float* Dsk      = (const float*)d_in[8];  // L,E,D
    const float* Wq       = (const float*)d_in[9];  // D,D
    const float* bq       = (const float*)d_in[10]; // D

    float* out_logits = (float*)d_out;                            // B*N
    float* out_states = out_logits + (size_t)BSZ * NSZ;           // L*E*B*DS
    float* out_loss   = out_states + (size_t)LNUM * ENUM * BSZ * SSZ;  // 1

    // workspace layout
    float* ws_h   = (float*)d_ws;                 // B*D
    float* ws_q   = ws_h + (size_t)BSZ * DSZ;     // B*D
    float* ws_acc = ws_q + (size_t)BSZ * DSZ;     // L*2*E floats

    hipMemsetAsync(ws_acc, 0, sizeof(float) * LNUM * 2 * ENUM, stream);

    const float* h_cur = token;  // token[:,0,:] is contiguous B*D
    for (int l = 0; l < LNUM; ++l) {
        layer_kernel<<<BSZ, 256, 0, stream>>>(
            h_cur, ws_h,
            Wg  + (size_t)l * DSZ * ENUM,
            bg  + (size_t)l * ENUM,
            A   + (size_t)l * ENUM * SSZ,
            Bin + (size_t)l * ENUM * DSZ * SSZ,
            Cout+ (size_t)l * ENUM * SSZ * DSZ,
            Dsk + (size_t)l * ENUM * DSZ,
            states + (size_t)l * ENUM * BSZ * SSZ,
            out_states + (size_t)l * ENUM * BSZ * SSZ,
            ws_acc + (l * 2 + 0) * ENUM,
            ws_acc + (l * 2 + 1) * ENUM);
        h_cur = ws_h;
    }

    q_kernel<<<BSZ, 256, 0, stream>>>(ws_h, Wq, bq, ws_q);

    dim3 lg(NSZ / 128, BSZ);
    logits_kernel<<<lg, 256, 0, stream>>>(ws_q, node_emb, out_logits);

    loss_kernel<<<1, 64, 0, stream>>>(ws_acc, out_loss);
}

// Round 3
// 183.678 us; speedup vs baseline: 2.6504x; 2.6504x over previous
//
#include <hip/hip_runtime.h>
#include <math.h>

#define LNUM 3
#define ENUM 8
#define TOPK 2
#define BSZ 256
#define NSZ 1024
#define DSZ 512
#define SSZ 128   // DS

typedef float f32x4 __attribute__((ext_vector_type(4)));

// ---------------- layer kernel ----------------
// grid = BSZ blocks, block = 1024 threads (16 waves). Block b handles token b.
// LAST=true additionally computes q = h_new @ Wq + bq for its row.
template <bool LAST>
__global__ __launch_bounds__(1024) void layer_kernel(
    const float* __restrict__ h_in,    // [B][D]
    float* __restrict__ h_out,         // [B][D] (unused when LAST)
    const float* __restrict__ Wg,      // [D][E]   (layer slice)
    const float* __restrict__ bg,      // [E]
    const float* __restrict__ A,       // [E][DS]
    const float* __restrict__ Bin,     // [E][D][DS]
    const float* __restrict__ Cout,    // [E][DS][D]
    const float* __restrict__ Dsk,     // [E][D]
    const float* __restrict__ states,  // [E][B][DS] (layer slice)
    float* __restrict__ out_states,    // [E][B][DS]
    float* __restrict__ acc_probs,     // [E]
    float* __restrict__ acc_sel,       // [E]
    const float* __restrict__ Wq,      // [D][D]  (LAST only)
    const float* __restrict__ bq,      // [D]     (LAST only)
    float* __restrict__ q_out)         // [B][D]  (LAST only)
{
    const int b = blockIdx.x;
    const int t = threadIdx.x;
    const int wave = t >> 6;
    const int lane = t & 63;

    __shared__ float h_s[DSZ];
    __shared__ float logit_s[ENUM];
    __shared__ float snew_s[TOPK][SSZ];
    __shared__ float part[1024];

    // load h row
    if (t < DSZ) h_s[t] = h_in[b * DSZ + t];
    __syncthreads();

    // gating logits: wave w computes expert w (8 of 16 waves active)
    if (wave < ENUM) {
        float p = 0.f;
        for (int d = lane; d < DSZ; d += 64) p = fmaf(h_s[d], Wg[d * ENUM + wave], p);
        for (int off = 32; off; off >>= 1) p += __shfl_down(p, off, 64);
        if (lane == 0) logit_s[wave] = p + bg[wave];
    }
    __syncthreads();

    // every thread computes softmax + top2 redundantly (identical results)
    float probs[ENUM];
    float mx = logit_s[0];
    for (int e = 1; e < ENUM; ++e) mx = fmaxf(mx, logit_s[e]);
    float ssum = 0.f;
    for (int e = 0; e < ENUM; ++e) { probs[e] = expf(logit_s[e] - mx); ssum += probs[e]; }
    const float sinv = 1.f / ssum;
    for (int e = 0; e < ENUM; ++e) probs[e] *= sinv;

    int i0 = 0;
    for (int e = 1; e < ENUM; ++e) if (probs[e] > probs[i0]) i0 = e;
    int i1 = -1;
    for (int e = 0; e < ENUM; ++e) {
        if (e == i0) continue;
        if (i1 < 0 || probs[e] > probs[i1]) i1 = e;
    }
    float g0 = probs[i0], g1 = probs[i1];
    const float ginv = 1.f / (g0 + g1);
    g0 *= ginv; g1 *= ginv;

    if (t < ENUM) {
        atomicAdd(&acc_probs[t], probs[t]);
        atomicAdd(&acc_sel[t], (t == i0 || t == i1) ? 1.0f : 0.0f);
    }

    // ---- s_new accumulate: t -> (k = t>>9, c = (t&511)>>7, s = t&127) ----
    {
        const int k = t >> 9;
        const int r = t & 511;
        const int c = r >> 7;          // 0..3, K-chunk of 128
        const int s = r & 127;
        const int e = k ? i1 : i0;
        const float* Bp = Bin + (size_t)e * DSZ * SSZ + (size_t)(c * 128) * SSZ + s;
        const float* hp = h_s + c * 128;
        float acc = 0.f;
        #pragma unroll 8
        for (int d = 0; d < 128; ++d) acc = fmaf(hp[d], Bp[d * SSZ], acc);
        part[t] = acc;
    }
    __syncthreads();

    // combine + decay -> snew_s
    if (t < TOPK * SSZ) {
        const int k = t >> 7;
        const int s = t & 127;
        const int e = k ? i1 : i0;
        const int base = k * 512 + s;
        const float sum = part[base] + part[base + 128] + part[base + 256] + part[base + 384];
        const float a = A[e * SSZ + s];
        const float decay = 1.f / (1.f + expf(-a));
        const float sv = states[((size_t)e * BSZ + b) * SSZ + s];
        snew_s[k][s] = decay * sv + sum;
    }
    __syncthreads();

    // write new_states (all 8 experts x 128) — 1 element/thread
    {
        const int e = t >> 7;
        const int s = t & 127;
        float v;
        if (e == i0)      v = snew_s[0][s];
        else if (e == i1) v = snew_s[1][s];
        else              v = states[((size_t)e * BSZ + b) * SSZ + s];
        out_states[((size_t)e * BSZ + b) * SSZ + s] = v;
    }

    // ---- y accumulate: t -> (half = t>>9 selects expert, d = t&511) ----
    {
        const int half = t >> 9;
        const int d = t & 511;
        const int e = half ? i1 : i0;
        const float* Cp = Cout + (size_t)e * SSZ * DSZ + d;
        const float* sp = snew_s[half];
        float acc = 0.f;
        #pragma unroll 8
        for (int s = 0; s < SSZ; ++s) acc = fmaf(sp[s], Cp[s * DSZ], acc);
        part[t] = acc;
    }
    __syncthreads();

    // combine: h_new = h + g0*y0 + g1*y1
    if (t < DSZ) {
        const float hd = h_s[t];
        const float y0 = part[t]       + hd * Dsk[i0 * DSZ + t];
        const float y1 = part[t + 512] + hd * Dsk[i1 * DSZ + t];
        const float hn = hd + g0 * y0 + g1 * y1;
        if (LAST) h_s[t] = hn;           // keep for q-phase
        else      h_out[b * DSZ + t] = hn;
    }

    if (LAST) {
        __syncthreads();
        // q accumulate: t -> (c = t>>9, d = t&511), K-chunks of 256
        {
            const int c = t >> 9;
            const int d = t & 511;
            const float* Wp = Wq + (size_t)(c * 256) * DSZ + d;
            const float* hp = h_s + c * 256;
            float acc = 0.f;
            #pragma unroll 8
            for (int dd = 0; dd < 256; ++dd) acc = fmaf(hp[dd], Wp[dd * DSZ], acc);
            part[t] = acc;
        }
        __syncthreads();
        if (t < DSZ) q_out[b * DSZ + t] = bq[t] + part[t] + part[t + 512];
    }
}

// ---------------- logits[b,n] = q[b] . node_emb[b,n,:] / sqrt(D) ----------------
// grid = (8, B), block = 256 (4 waves). Each wave: 32 n's, one row-dot each.
// Block (0,0) thread 0 additionally finishes lb_loss.
__global__ __launch_bounds__(256) void logits_kernel(
    const float* __restrict__ q, const float* __restrict__ node_emb,
    float* __restrict__ logits,
    const float* __restrict__ acc, float* __restrict__ loss_out)
{
    const int b = blockIdx.y;
    const int wave = threadIdx.x >> 6;
    const int lane = threadIdx.x & 63;

    if (blockIdx.x == 0 && blockIdx.y == 0 && threadIdx.x == 0) {
        float lb = 0.f;
        for (int l = 0; l < LNUM; ++l)
            for (int e = 0; e < ENUM; ++e) {
                const float mp = acc[(l * 2 + 0) * ENUM + e] * (1.0f / BSZ);
                const float ms = acc[(l * 2 + 1) * ENUM + e] * (1.0f / BSZ);
                lb += (float)ENUM * mp * ms;
            }
        loss_out[0] = lb;
    }

    const f32x4* q4 = (const f32x4*)(q + b * DSZ);
    const f32x4 q0 = q4[lane];
    const f32x4 q1 = q4[lane + 64];
    const float scale = 0.04419417382415922f;  // 1/sqrt(512)

    const int n0 = blockIdx.x * 128 + wave * 32;
    #pragma unroll 2
    for (int i = 0; i < 32; ++i) {
        const int n = n0 + i;
        const f32x4* r = (const f32x4*)(node_emb + ((size_t)b * NSZ + n) * DSZ);
        const f32x4 a0 = __builtin_nontemporal_load(&r[lane]);
        const f32x4 a1 = __builtin_nontemporal_load(&r[lane + 64]);
        float dot = a0.x * q0.x + a0.y * q0.y + a0.z * q0.z + a0.w * q0.w
                  + a1.x * q1.x + a1.y * q1.y + a1.z * q1.z + a1.w * q1.w;
        for (int off = 32; off; off >>= 1) dot += __shfl_down(dot, off, 64);
        if (lane == 0) logits[b * NSZ + n] = dot * scale;
    }
}

extern "C" void kernel_launch(void* const* d_in, const int* in_sizes, int n_in,
                              void* d_out, int out_size, void* d_ws, size_t ws_size,
                              hipStream_t stream) {
    const float* token    = (const float*)d_in[0];  // B,1,D
    const float* node_emb = (const float*)d_in[1];  // B,N,D
    const float* states   = (const float*)d_in[2];  // L,E,B,DS
    const float* Wg       = (const float*)d_in[3];  // L,D,E
    const float* bg       = (const float*)d_in[4];  // L,E
    const float* A        = (const float*)d_in[5];  // L,E,DS
    const float* Bin      = (const float*)d_in[6];  // L,E,D,DS
    const float* Cout     = (const float*)d_in[7];  // L,E,DS,D
    const float* Dsk      = (const float*)d_in[8];  // L,E,D
    const float* Wq       = (const float*)d_in[9];  // D,D
    const float* bq       = (const float*)d_in[10]; // D

    float* out_logits = (float*)d_out;                            // B*N
    float* out_states = out_logits + (size_t)BSZ * NSZ;           // L*E*B*DS
    float* out_loss   = out_states + (size_t)LNUM * ENUM * BSZ * SSZ;  // 1

    // workspace layout
    float* ws_h   = (float*)d_ws;                 // B*D
    float* ws_q   = ws_h + (size_t)BSZ * DSZ;     // B*D
    float* ws_acc = ws_q + (size_t)BSZ * DSZ;     // L*2*E floats

    (void)hipMemsetAsync(ws_acc, 0, sizeof(float) * LNUM * 2 * ENUM, stream);

    const float* h_cur = token;  // token[:,0,:] is contiguous B*D
    for (int l = 0; l < LNUM; ++l) {
        const bool last = (l == LNUM - 1);
        auto kern = last ? layer_kernel<true> : layer_kernel<false>;
        kern<<<BSZ, 1024, 0, stream>>>(
            h_cur, ws_h,
            Wg  + (size_t)l * DSZ * ENUM,
            bg  + (size_t)l * ENUM,
            A   + (size_t)l * ENUM * SSZ,
            Bin + (size_t)l * ENUM * DSZ * SSZ,
            Cout+ (size_t)l * ENUM * SSZ * DSZ,
            Dsk + (size_t)l * ENUM * DSZ,
            states + (size_t)l * ENUM * BSZ * SSZ,
            out_states + (size_t)l * ENUM * BSZ * SSZ,
            ws_acc + (l * 2 + 0) * ENUM,
            ws_acc + (l * 2 + 1) * ENUM,
            Wq, bq, ws_q);
        h_cur = ws_h;
    }

    dim3 lg(NSZ / 128, BSZ);
    logits_kernel<<<lg, 256, 0, stream>>>(ws_q, node_emb, out_logits, ws_acc, out_loss);
}

// Round 4
// 172.516 us; speedup vs baseline: 2.8219x; 1.0647x over previous
//
#include <hip/hip_runtime.h>
#include <math.h>

#define LNUM 3
#define ENUM 8
#define TOPK 2
#define BSZ 256
#define NSZ 1024
#define DSZ 512
#define SSZ 128   // DS

typedef float f32x4 __attribute__((ext_vector_type(4)));

// ---------------- fused kernel: 3 layers + q ----------------
// grid = BSZ blocks, block = 1024 threads (16 waves). Block b owns token b.
// h lives in LDS across all layers; no global h traffic at all.
__global__ __launch_bounds__(1024, 2) void fused_kernel(
    const float* __restrict__ token,   // [B][D]
    const float* __restrict__ states,  // [L][E][B][DS]
    const float* __restrict__ Wg,      // [L][D][E]
    const float* __restrict__ bg,      // [L][E]
    const float* __restrict__ A,       // [L][E][DS]
    const float* __restrict__ Bin,     // [L][E][D][DS]
    const float* __restrict__ Cout,    // [L][E][DS][D]
    const float* __restrict__ Dsk,     // [L][E][D]
    const float* __restrict__ Wq,      // [D][D]
    const float* __restrict__ bq,      // [D]
    float* __restrict__ out_states,    // [L][E][B][DS]
    float* __restrict__ acc,           // [L][2][E] (probs, sel) — pre-zeroed
    float* __restrict__ q_out)         // [B][D]
{
    const int b = blockIdx.x;
    const int t = threadIdx.x;
    const int wave = t >> 6;
    const int lane = t & 63;
    const int ehalf = t >> 9;          // 0/1: which selected expert this thread serves

    __shared__ float h_s[DSZ];
    __shared__ float snew_s[TOPK][SSZ];
    __shared__ float logit_s[ENUM];
    __shared__ f32x4 part4[1024];      // 16 KB scratch, reused every phase
    float* part = (float*)part4;

    if (t < DSZ) h_s[t] = token[b * DSZ + t];

    for (int l = 0; l < LNUM; ++l) {
        const float* Wg_l  = Wg  + (size_t)l * DSZ * ENUM;
        const float* bg_l  = bg  + (size_t)l * ENUM;
        const float* A_l   = A   + (size_t)l * ENUM * SSZ;
        const float* Bin_l = Bin + (size_t)l * ENUM * DSZ * SSZ;
        const float* Cou_l = Cout+ (size_t)l * ENUM * SSZ * DSZ;
        const float* Dsk_l = Dsk + (size_t)l * ENUM * DSZ;
        const float* st_l  = states     + (size_t)l * ENUM * BSZ * SSZ;
        float*       os_l  = out_states + (size_t)l * ENUM * BSZ * SSZ;

        // stage Wg[l] (16 KB) into part; also fences h_s (l=0 load / l-1 update)
        __syncthreads();
        part4[t] = ((const f32x4*)Wg_l)[t];
        __syncthreads();

        // gating logits: wave w computes expert w
        if (wave < ENUM) {
            float p = 0.f;
            #pragma unroll
            for (int i = 0; i < 8; ++i) {
                const int d = lane + i * 64;
                p = fmaf(h_s[d], part[d * ENUM + wave], p);
            }
            for (int off = 32; off; off >>= 1) p += __shfl_down(p, off, 64);
            if (lane == 0) logit_s[wave] = p + bg_l[wave];
        }
        __syncthreads();

        // softmax + top2, redundantly per thread (identical results)
        float probs[ENUM];
        float mx = logit_s[0];
        for (int e = 1; e < ENUM; ++e) mx = fmaxf(mx, logit_s[e]);
        float ssum = 0.f;
        for (int e = 0; e < ENUM; ++e) { probs[e] = expf(logit_s[e] - mx); ssum += probs[e]; }
        const float sinv = 1.f / ssum;
        for (int e = 0; e < ENUM; ++e) probs[e] *= sinv;

        int i0 = 0;
        for (int e = 1; e < ENUM; ++e) if (probs[e] > probs[i0]) i0 = e;
        int i1 = -1;
        for (int e = 0; e < ENUM; ++e) {
            if (e == i0) continue;
            if (i1 < 0 || probs[e] > probs[i1]) i1 = e;
        }
        float g0 = probs[i0], g1 = probs[i1];
        const float ginv = 1.f / (g0 + g1);
        g0 *= ginv; g1 *= ginv;

        if (t < ENUM) {
            atomicAdd(&acc[(l * 2 + 0) * ENUM + t], probs[t]);
            atomicAdd(&acc[(l * 2 + 1) * ENUM + t], (t == i0 || t == i1) ? 1.0f : 0.0f);
        }
        const int esel = ehalf ? i1 : i0;

        // ---- s_new partials: t -> (ehalf, c = d-chunk of 32, squad) ----
        {
            const int rem   = t & 511;
            const int c     = rem >> 5;      // 0..15
            const int squad = rem & 31;      // s = squad*4
            const float* Bp = Bin_l + (size_t)esel * DSZ * SSZ;
            const int d0 = c * 32;
            f32x4 acc4 = {0.f, 0.f, 0.f, 0.f};
            #pragma unroll
            for (int d = 0; d < 32; ++d)
                acc4 += *(const f32x4*)(Bp + (size_t)(d0 + d) * SSZ + squad * 4) * h_s[d0 + d];
            part4[(ehalf * 16 + c) * 32 + squad] = acc4;
        }
        __syncthreads();

        // combine + decay -> snew_s
        if (t < TOPK * SSZ) {
            const int k = t >> 7, s = t & 127;
            const int e = k ? i1 : i0;
            float sum = 0.f;
            #pragma unroll
            for (int c = 0; c < 16; ++c) sum += part[(k * 16 + c) * 128 + s];
            const float a = A_l[e * SSZ + s];
            const float decay = 1.f / (1.f + expf(-a));
            snew_s[k][s] = decay * st_l[((size_t)e * BSZ + b) * SSZ + s] + sum;
        }
        __syncthreads();

        // write new_states for all 8 experts (1 elem/thread)
        {
            const int e = t >> 7, s = t & 127;
            float v;
            if (e == i0)      v = snew_s[0][s];
            else if (e == i1) v = snew_s[1][s];
            else              v = st_l[((size_t)e * BSZ + b) * SSZ + s];
            os_l[((size_t)e * BSZ + b) * SSZ + s] = v;
        }

        // ---- y partials: t -> (ehalf, chunk = s-chunk of 32, dquad) ----
        {
            const int rem   = t & 511;
            const int chunk = rem >> 7;      // 0..3
            const int dquad = rem & 127;     // d = dquad*4
            const float* Cp = Cou_l + (size_t)esel * SSZ * DSZ;
            const float* sp = snew_s[ehalf];
            const int s0 = chunk * 32;
            f32x4 acc4 = {0.f, 0.f, 0.f, 0.f};
            #pragma unroll
            for (int s = 0; s < 32; ++s)
                acc4 += *(const f32x4*)(Cp + (size_t)(s0 + s) * DSZ + dquad * 4) * sp[s0 + s];
            part4[(ehalf * 4 + chunk) * 128 + dquad] = acc4;
        }
        __syncthreads();

        // h update: h_new = h + g0*y0 + g1*y1
        if (t < DSZ) {
            const float hd = h_s[t];
            float y0 = hd * Dsk_l[i0 * DSZ + t];
            float y1 = hd * Dsk_l[i1 * DSZ + t];
            #pragma unroll
            for (int c = 0; c < 4; ++c) {
                y0 += part[c * 512 + t];
                y1 += part[(4 + c) * 512 + t];
            }
            h_s[t] = hd + g0 * y0 + g1 * y1;
        }
    }

    // ---- q = h @ Wq + bq ----
    __syncthreads();
    {
        const int chunk = t >> 7;        // 0..7, dd-chunk of 64
        const int dquad = t & 127;
        const int dd0 = chunk * 64;
        f32x4 acc4 = {0.f, 0.f, 0.f, 0.f};
        #pragma unroll 8
        for (int i = 0; i < 64; ++i)
            acc4 += *(const f32x4*)(Wq + (size_t)(dd0 + i) * DSZ + dquad * 4) * h_s[dd0 + i];
        part4[chunk * 128 + dquad] = acc4;
    }
    __syncthreads();
    if (t < DSZ) {
        float qv = bq[t];
        #pragma unroll
        for (int c = 0; c < 8; ++c) qv += part[c * 512 + t];
        q_out[b * DSZ + t] = qv;
    }
}

// ---------------- logits[b,n] = q[b] . node_emb[b,n,:] / sqrt(D) ----------------
// grid = (8, B), block = 256 (4 waves). Each wave: 32 n's, one row-dot each.
// Block (0,0) thread 0 additionally finishes lb_loss.
__global__ __launch_bounds__(256) void logits_kernel(
    const float* __restrict__ q, const float* __restrict__ node_emb,
    float* __restrict__ logits,
    const float* __restrict__ acc, float* __restrict__ loss_out)
{
    const int b = blockIdx.y;
    const int wave = threadIdx.x >> 6;
    const int lane = threadIdx.x & 63;

    if (blockIdx.x == 0 && blockIdx.y == 0 && threadIdx.x == 0) {
        float lb = 0.f;
        for (int l = 0; l < LNUM; ++l)
            for (int e = 0; e < ENUM; ++e) {
                const float mp = acc[(l * 2 + 0) * ENUM + e] * (1.0f / BSZ);
                const float ms = acc[(l * 2 + 1) * ENUM + e] * (1.0f / BSZ);
                lb += (float)ENUM * mp * ms;
            }
        loss_out[0] = lb;
    }

    const f32x4* q4 = (const f32x4*)(q + b * DSZ);
    const f32x4 q0 = q4[lane];
    const f32x4 q1 = q4[lane + 64];
    const float scale = 0.04419417382415922f;  // 1/sqrt(512)

    const int n0 = blockIdx.x * 128 + wave * 32;
    #pragma unroll 2
    for (int i = 0; i < 32; ++i) {
        const int n = n0 + i;
        const f32x4* r = (const f32x4*)(node_emb + ((size_t)b * NSZ + n) * DSZ);
        const f32x4 a0 = __builtin_nontemporal_load(&r[lane]);
        const f32x4 a1 = __builtin_nontemporal_load(&r[lane + 64]);
        float dot = a0.x * q0.x + a0.y * q0.y + a0.z * q0.z + a0.w * q0.w
                  + a1.x * q1.x + a1.y * q1.y + a1.z * q1.z + a1.w * q1.w;
        for (int off = 32; off; off >>= 1) dot += __shfl_down(dot, off, 64);
        if (lane == 0) logits[b * NSZ + n] = dot * scale;
    }
}

extern "C" void kernel_launch(void* const* d_in, const int* in_sizes, int n_in,
                              void* d_out, int out_size, void* d_ws, size_t ws_size,
                              hipStream_t stream) {
    const float* token    = (const float*)d_in[0];  // B,1,D
    const float* node_emb = (const float*)d_in[1];  // B,N,D
    const float* states   = (const float*)d_in[2];  // L,E,B,DS
    const float* Wg       = (const float*)d_in[3];  // L,D,E
    const float* bg       = (const float*)d_in[4];  // L,E
    const float* A        = (const float*)d_in[5];  // L,E,DS
    const float* Bin      = (const float*)d_in[6];  // L,E,D,DS
    const float* Cout     = (const float*)d_in[7];  // L,E,DS,D
    const float* Dsk      = (const float*)d_in[8];  // L,E,D
    const float* Wq       = (const float*)d_in[9];  // D,D
    const float* bq       = (const float*)d_in[10]; // D

    float* out_logits = (float*)d_out;                            // B*N
    float* out_states = out_logits + (size_t)BSZ * NSZ;           // L*E*B*DS
    float* out_loss   = out_states + (size_t)LNUM * ENUM * BSZ * SSZ;  // 1

    // workspace layout
    float* ws_q   = (float*)d_ws;                 // B*D
    float* ws_acc = ws_q + (size_t)BSZ * DSZ;     // L*2*E floats

    (void)hipMemsetAsync(ws_acc, 0, sizeof(float) * LNUM * 2 * ENUM, stream);

    fused_kernel<<<BSZ, 1024, 0, stream>>>(
        token, states, Wg, bg, A, Bin, Cout, Dsk, Wq, bq,
        out_states, ws_acc, ws_q);

    dim3 lg(NSZ / 128, BSZ);
    logits_kernel<<<lg, 256, 0, stream>>>(ws_q, node_emb, out_logits, ws_acc, out_loss);
}